// Round 10
// baseline (272.650 us; speedup 1.0000x reference)
//
#include <hip/hip_runtime.h>
#include <hip/hip_bf16.h>
#include <stdint.h>

#define NB 8192
#define NE 210
#define NS 7
#define NEXP 217
#define NI 8
#define H 128
#define BT 512
#define NTILE (NB / BT)          // 16
// blob per expert: [W1t 4K][bias 2K: bH0,bH1,wo,bo][Wh0 32K][Wh1 32K]
#define BLOB_STRIDE 71680
#define BIAS_OFF 4096
#define WH0_OFF 6144
#define WH1_OFF 38912
#define SMEM_BYTES 67584         // 2K bias + 64K Wh -> 2 blocks/CU

// ws layout (bytes)
#define O_BLOB 0u
#define O_F    16000000u
#define O_FS   43525120u
#define O_PART 43754496u

typedef __attribute__((ext_vector_type(8))) short bf16x8;
typedef __attribute__((ext_vector_type(4))) float f32x4;
typedef __attribute__((ext_vector_type(16))) float f32x16;
typedef __attribute__((ext_vector_type(2))) int i32x2;

union I4V { int4 i; bf16x8 v; unsigned u[4]; };
union C16 { f32x16 v; f32x4 q[4]; };

__device__ __forceinline__ unsigned short f2bf(float f) {
  unsigned u = __float_as_uint(f);
  u += 0x7fffu + ((u >> 16) & 1u);
  return (unsigned short)(u >> 16);
}
__device__ __forceinline__ float fast_tanh(float x) {
  // tanh(x) = 1 - 2/(1 + 2^(2*log2(e)*x)); saturates correctly at +-inf
  float e = __builtin_amdgcn_exp2f(2.8853900817779268f * x);
  return 1.0f - 2.0f * __builtin_amdgcn_rcpf(1.0f + e);
}
__device__ __forceinline__ unsigned pk_bf16(float a, float b) {
  unsigned r;
  asm("v_cvt_pk_bf16_f32 %0, %1, %2" : "=v"(r) : "v"(a), "v"(b));
  return r;
}
__device__ __forceinline__ void glds16(const void* g, void* l) {
  __builtin_amdgcn_global_load_lds(
      (const __attribute__((address_space(1))) unsigned int*)g,
      (__attribute__((address_space(3))) unsigned int*)l, 16, 0, 0);
}

// ---- inter-layer transition (verified R5 permlane mapping) ---------------
__device__ __forceinline__ void transition(const f32x16 (&acc)[4], bf16x8 (&bn)[8]) {
#pragma unroll
  for (int kk = 0; kk < 8; ++kk) {
    const int ms = kk >> 1, ko = (kk & 1) * 8;
    unsigned P0 = pk_bf16(fast_tanh(acc[ms][ko + 0]), fast_tanh(acc[ms][ko + 1]));
    unsigned P1 = pk_bf16(fast_tanh(acc[ms][ko + 2]), fast_tanh(acc[ms][ko + 3]));
    unsigned P2 = pk_bf16(fast_tanh(acc[ms][ko + 4]), fast_tanh(acc[ms][ko + 5]));
    unsigned P3 = pk_bf16(fast_tanh(acc[ms][ko + 6]), fast_tanh(acc[ms][ko + 7]));
    i32x2 s0 = __builtin_amdgcn_permlane32_swap((int)P0, (int)P2, false, false);
    i32x2 s1 = __builtin_amdgcn_permlane32_swap((int)P1, (int)P3, false, false);
    I4V r;
    r.u[0] = (unsigned)s0.x;   // w0
    r.u[1] = (unsigned)s1.x;   // w1
    r.u[2] = (unsigned)s0.y;   // w2
    r.u[3] = (unsigned)s1.y;   // w3
    bn[kk] = r.v;
  }
}

// ---- one hidden layer: K=128 as 8 k-slices; bias enters as C of kk=0 ------
__device__ __forceinline__ void hidden_layer(f32x16 (&acc)[4], const bf16x8 (&bn)[8],
                                             const uint8_t* wb, const float* biaL,
                                             int row, int hi, int hi4) {
  {
    int soff0 = (hi ^ (row & 15)) << 4;
#pragma unroll
    for (int mt = 0; mt < 4; ++mt) {
      bf16x8 aF = *(const bf16x8*)(wb + (mt * 32 + row) * 256 + soff0);
      C16 c0;
#pragma unroll
      for (int i = 0; i < 4; ++i)
        c0.q[i] = *(const f32x4*)(biaL + mt * 32 + i * 8 + hi4);
      acc[mt] = __builtin_amdgcn_mfma_f32_32x32x16_bf16(aF, bn[0], c0.v, 0, 0, 0);
    }
  }
#pragma unroll
  for (int kk = 1; kk < 8; ++kk) {
    int soff = ((2 * kk + hi) ^ (row & 15)) << 4;
#pragma unroll
    for (int mt = 0; mt < 4; ++mt) {
      bf16x8 aF = *(const bf16x8*)(wb + (mt * 32 + row) * 256 + soff);
      acc[mt] = __builtin_amdgcn_mfma_f32_32x32x16_bf16(aF, bn[kk], acc[mt], 0, 0, 0);
    }
  }
}

// ---- layer 1 + full expert pipeline for one 256-row group ----------------
__device__ __forceinline__ void run_group(
    const I4V (&aW)[4], const C16 (&c1)[4], const I4V& bfr,
    const uint8_t* smem, float* __restrict__ partial,
    size_t pbase, int row, int hi, int hi4) {
  f32x16 acc[4];
#pragma unroll
  for (int mt = 0; mt < 4; ++mt)
    acc[mt] = __builtin_amdgcn_mfma_f32_32x32x16_bf16(aW[mt].v, bfr.v, c1[mt].v, 0, 0, 0);
  bf16x8 bn[8];
  transition(acc, bn);
  hidden_layer(acc, bn, smem + 2048, (const float*)smem, row, hi, hi4);
  transition(acc, bn);
  hidden_layer(acc, bn, smem + 34816, (const float*)(smem + 512), row, hi, hi4);
  const float* woL = (const float*)(smem + 1024);
  float bout = *(const float*)(smem + 1536);
  float sum = 0.f;
#pragma unroll
  for (int mt = 0; mt < 4; ++mt)
#pragma unroll
    for (int i = 0; i < 4; ++i) {
      f32x4 wq = *(const f32x4*)(woL + mt * 32 + i * 8 + hi4);
#pragma unroll
      for (int j = 0; j < 4; ++j)
        sum += fast_tanh(acc[mt][4 * i + j]) * wq[j];
    }
  sum += __shfl_xor(sum, 32);
  if (hi == 0)
    partial[pbase] = sum + bout;
}

// ---------------- weight pack (R7, no folding) -----------------------------
__global__ __launch_bounds__(128) void k_pack(
    const float* __restrict__ W1, const float* __restrict__ Wh,
    const float* __restrict__ W1s, const float* __restrict__ Whs,
    const float* __restrict__ bh, const float* __restrict__ bhs,
    const float* __restrict__ Wo, const float* __restrict__ Wos,
    const float* __restrict__ bo, const float* __restrict__ bos,
    uint8_t* __restrict__ blob) {
  int bid = blockIdx.x;
  int e = bid / 3, sec = bid % 3;
  int n = threadIdx.x;
  uint8_t* be = blob + (size_t)e * BLOB_STRIDE;
  bool big = e < NE;
  int s = e - NE;
  if (sec == 0) {
    // W1t: 128 rows x 32B (K=16, real k 0..7, rest zero), linear
    union { int4 v[2]; unsigned short u[16]; } row;
    row.v[0] = make_int4(0, 0, 0, 0);
    row.v[1] = make_int4(0, 0, 0, 0);
    if (big) {
      for (int k = 0; k < NI; ++k) row.u[k] = f2bf(W1[((size_t)e * NI + k) * H + n]);
    } else {
      for (int k = 0; k < 2; ++k) row.u[k] = f2bf(W1s[((size_t)s * 2 + k) * H + n]);
    }
    *(int4*)(be + n * 32) = row.v[0];
    *(int4*)(be + n * 32 + 16) = row.v[1];
    // bias section: bH0[0:128] | bH1[128:256] | wo[256:384] | bo[384]
    float* bsec = (float*)(be + BIAS_OFF);
    bsec[n]       = big ? bh[(size_t)e * H + n]          : bhs[(size_t)s * H + n];
    bsec[128 + n] = big ? bh[((size_t)NE + e) * H + n]   : bhs[((size_t)NS + s) * H + n];
    bsec[256 + n] = big ? Wo[(size_t)e * H + n]          : Wos[(size_t)s * H + n];
    if (n == 0) bsec[384] = big ? bo[e] : bos[s];
  } else {
    int l = sec - 1;
    union { int4 v[16]; unsigned short u[128]; } row;
    if (big) {
      for (int k = 0; k < H; ++k)
        row.u[k] = f2bf(Wh[(((size_t)l * NE + e) * H + k) * H + n]);
    } else {
      for (int k = 0; k < H; ++k)
        row.u[k] = f2bf(Whs[(((size_t)l * NS + s) * H + k) * H + n]);
    }
    int4* dst = (int4*)(be + (l ? WH1_OFF : WH0_OFF) + n * 256);
    for (int c = 0; c < 16; ++c) dst[c] = row.v[c ^ (n & 15)];
  }
}

// ---------------- F build: normalize + gather, bf16 -----------------------
__global__ __launch_bounds__(256) void k_fbuild(
    const float* __restrict__ F_dist, const float* __restrict__ F_cos,
    const float* __restrict__ F_sin,
    const float* __restrict__ Zd, const float* __restrict__ Zc,
    const float* __restrict__ Zs,
    const int* __restrict__ IDX3, const int* __restrict__ IDX5,
    uint16_t* __restrict__ F, uint16_t* __restrict__ Fs) {
  int bid = blockIdx.x;
  int e = bid >> 5, tile = bid & 31;
  int b = tile * 256 + threadIdx.x;
  if (e < NE) {
    float cv = (F_cos[(size_t)b * NE + e] - Zc[e]) / Zc[NE + e];
    float sv = (F_sin[(size_t)b * NE + e] - Zs[e]) / Zs[NE + e];
    union { int4 v; unsigned short u[8]; } o;
    for (int j = 0; j < 6; ++j) {
      int id = IDX3[e * 6 + j];
      float x = (F_dist[(size_t)b * 45 + id] - Zd[id]) / Zd[45 + id];
      o.u[j] = f2bf(x);
    }
    o.u[6] = f2bf(cv);
    o.u[7] = f2bf(sv);
    *(int4*)(F + ((size_t)e * NB + b) * 8) = o.v;
  } else {
    int s = e - NE;
    int id = IDX5[s];
    float cv = (F_cos[(size_t)b * NE + id] - Zc[id]) / Zc[NE + id];
    float sv = (F_sin[(size_t)b * NE + id] - Zs[id]) / Zs[NE + id];
    unsigned o = (unsigned)f2bf(cv) | ((unsigned)f2bf(sv) << 16);
    *(unsigned*)(Fs + ((size_t)s * NB + b) * 2) = o;
  }
}

// ---------------- main: 3-layer MLP, two 256-row groups per staging -------
__global__ __launch_bounds__(512, 4) void k_main(
    const uint8_t* __restrict__ blob,
    const uint16_t* __restrict__ F, const uint16_t* __restrict__ Fs,
    const float* __restrict__ b1, const float* __restrict__ b1s,
    float* __restrict__ partial) {
  extern __shared__ __attribute__((aligned(16))) uint8_t smem[];
  // smem: [0:2K bias/wo][2048: Wh0 32K][34816: Wh1 32K]

  int bid = blockIdx.x;
  const int TOT = NEXP * NTILE;    // 3472, divisible by 8
  int lb = (bid & 7) * (TOT >> 3) + (bid >> 3);   // XCD-chunked swizzle
  int e = lb >> 4;
  int tile = lb & 15;
  int brow = tile * BT;            // 512-row tile; two 256-row groups

  int t = threadIdx.x;
  int w = t >> 6, lane = t & 63;
  int row = lane & 31, hi = lane >> 5;
  int hi4 = hi << 2;

  bool big = e < NE;
  int s = e - NE;
  const uint8_t* be = blob + (size_t)e * BLOB_STRIDE;
  size_t fbase = big ? ((size_t)e * NB + brow + w * 32 + row)
                     : ((size_t)s * NB + brow + w * 32 + row);

  // ---- early VMEM for group 0 (issued BEFORE glds: in-order vmcnt =>
  //      waiting on these leaves the staging queue in flight) --------------
  I4V bfr0;
  bfr0.i = make_int4(0, 0, 0, 0);
  if (hi == 0) {
    if (big) bfr0.i = *(const int4*)(F + fbase * 8);
    else     bfr0.u[0] = *(const unsigned*)(Fs + fbase * 2);
  }
  const float* bias1 = big ? b1 + (size_t)e * H : b1s + (size_t)s * H;
  I4V aW[4];
  C16 c1[4];
#pragma unroll
  for (int mt = 0; mt < 4; ++mt) {
    aW[mt].i = *(const int4*)(be + (mt * 32 + row) * 32 + hi * 16);
#pragma unroll
    for (int i = 0; i < 4; ++i)
      c1[mt].q[i] = *(const f32x4*)(bias1 + mt * 32 + i * 8 + hi4);
  }
  __builtin_amdgcn_sched_barrier(0);

  // ---- phase A staging: bias(2) + Wh0(32) chunks; phase B: Wh1(32) -------
  for (int c = w; c < 34; c += 8)
    glds16(be + BIAS_OFF + c * 1024 + lane * 16, smem + c * 1024);
  __builtin_amdgcn_sched_barrier(0);
  for (int c = 34 + w; c < 66; c += 8)
    glds16(be + BIAS_OFF + c * 1024 + lane * 16, smem + c * 1024);
  __builtin_amdgcn_sched_barrier(0);

  // ---- group 0: layer 1 (no LDS) overlaps staging -------------------------
  f32x16 acc[4];
#pragma unroll
  for (int mt = 0; mt < 4; ++mt)
    acc[mt] = __builtin_amdgcn_mfma_f32_32x32x16_bf16(aW[mt].v, bfr0.v, c1[mt].v, 0, 0, 0);
  bf16x8 bn[8];
  transition(acc, bn);

  // phase A done (each wave's 4 youngest VMEM = its phase-B glds)
  asm volatile("s_waitcnt vmcnt(4)" ::: "memory");
  __builtin_amdgcn_s_barrier();
  __builtin_amdgcn_sched_barrier(0);

  hidden_layer(acc, bn, smem + 2048, (const float*)smem, row, hi, hi4);
  transition(acc, bn);

  asm volatile("s_waitcnt vmcnt(0)" ::: "memory");
  __builtin_amdgcn_s_barrier();
  __builtin_amdgcn_sched_barrier(0);

  hidden_layer(acc, bn, smem + 34816, (const float*)(smem + 512), row, hi, hi4);

  // ---- late re-loads for group 1 (opaque ptrs defeat CSE: keeps VGPR low;
  //      L2-hot, latency hides under group-0 output) ------------------------
  const uint8_t* be2 = be;
  asm("" : "+v"(be2));
  const float* bias1b = bias1;
  asm("" : "+v"(bias1b));
  I4V bfr1, aW2[4];
  C16 c12[4];
  bfr1.i = make_int4(0, 0, 0, 0);
  if (hi == 0) {
    if (big) bfr1.i = *(const int4*)(F + (fbase + 256) * 8);
    else     bfr1.u[0] = *(const unsigned*)(Fs + (fbase + 256) * 2);
  }
#pragma unroll
  for (int mt = 0; mt < 4; ++mt) {
    aW2[mt].i = *(const int4*)(be2 + (mt * 32 + row) * 32 + hi * 16);
#pragma unroll
    for (int i = 0; i < 4; ++i)
      c12[mt].q[i] = *(const f32x4*)(bias1b + mt * 32 + i * 8 + hi4);
  }

  // ---- group 0 output -----------------------------------------------------
  {
    const float* woL = (const float*)(smem + 1024);
    float bout = *(const float*)(smem + 1536);
    float sum = 0.f;
#pragma unroll
    for (int mt = 0; mt < 4; ++mt)
#pragma unroll
      for (int i = 0; i < 4; ++i) {
        f32x4 wq = *(const f32x4*)(woL + mt * 32 + i * 8 + hi4);
#pragma unroll
        for (int j = 0; j < 4; ++j)
          sum += fast_tanh(acc[mt][4 * i + j]) * wq[j];
      }
    sum += __shfl_xor(sum, 32);
    if (hi == 0)
      partial[(size_t)e * NB + brow + w * 32 + row] = sum + bout;
  }

  // ---- group 1: weights already resident, barrier-free --------------------
  run_group(aW2, c12, bfr1, smem, partial,
            (size_t)e * NB + brow + 256 + w * 32 + row, row, hi, hi4);
}

// ---------------- reduce over experts ------------------------------------
__global__ __launch_bounds__(256) void k_reduce(const float* __restrict__ partial,
                                                float* __restrict__ out) {
  int b = blockIdx.x * 256 + threadIdx.x;
  float s = 0.f;
  for (int e = 0; e < NEXP; ++e) s += partial[(size_t)e * NB + b];
  out[b] = s;
}

extern "C" void kernel_launch(void* const* d_in, const int* in_sizes, int n_in,
                              void* d_out, int out_size, void* d_ws, size_t ws_size,
                              hipStream_t stream) {
  const float* F_dist = (const float*)d_in[0];
  const float* F_cos  = (const float*)d_in[1];
  const float* F_sin  = (const float*)d_in[2];
  // d_in[3] F_angle unused by reference
  const float* Zd  = (const float*)d_in[4];
  const float* Zc  = (const float*)d_in[5];
  const float* Zs  = (const float*)d_in[6];
  const int* IDX3  = (const int*)d_in[7];
  const int* IDX5  = (const int*)d_in[8];
  const float* W1  = (const float*)d_in[9];
  const float* b1  = (const float*)d_in[10];
  const float* Wh  = (const float*)d_in[11];
  const float* bh  = (const float*)d_in[12];
  const float* Wo  = (const float*)d_in[13];
  const float* bo  = (const float*)d_in[14];
  const float* W1s = (const float*)d_in[15];
  const float* b1s = (const float*)d_in[16];
  const float* Whs = (const float*)d_in[17];
  const float* bhs = (const float*)d_in[18];
  const float* Wos = (const float*)d_in[19];
  const float* bos = (const float*)d_in[20];

  uint8_t* ws = (uint8_t*)d_ws;
  uint8_t* blob = ws + O_BLOB;
  uint16_t* F   = (uint16_t*)(ws + O_F);
  uint16_t* Fs  = (uint16_t*)(ws + O_FS);
  float* partial = (float*)(ws + O_PART);

  hipFuncSetAttribute(reinterpret_cast<const void*>(k_main),
                      hipFuncAttributeMaxDynamicSharedMemorySize, SMEM_BYTES);

  k_pack<<<NEXP * 3, 128, 0, stream>>>(W1, Wh, W1s, Whs, bh, bhs, Wo, Wos, bo, bos, blob);
  k_fbuild<<<NEXP * 32, 256, 0, stream>>>(F_dist, F_cos, F_sin, Zd, Zc, Zs,
                                          IDX3, IDX5, F, Fs);
  k_main<<<NEXP * NTILE, 512, SMEM_BYTES, stream>>>(blob, F, Fs, b1, b1s, partial);
  k_reduce<<<NB / 256, 256, 0, stream>>>(partial, (float*)d_out);
}

// Round 11
// 257.974 us; speedup vs baseline: 1.0569x; 1.0569x over previous
//
#include <hip/hip_runtime.h>
#include <hip/hip_bf16.h>
#include <stdint.h>

#define NB 8192
#define NE 210
#define NS 7
#define NEXP 217
#define NI 8
#define H 128
#define BT 256
#define NTILE (NB / BT)          // 32
// blob per expert: [W1k 4K][bias 2K: bH0k,bH1k,wo,bo][Wh0k 32K][Wh1k 32K]
#define BLOB_STRIDE 71680
#define BIAS_OFF 4096
#define WH0_OFF 6144
#define WH1_OFF 38912
#define SMEM_BYTES 67584         // 2K bias + 64K Wh -> 2 blocks/CU
#define K2 2.8853900817779268f   // 2/ln2 : tanh(x) = 1 - 2/(1+2^(K2 x))

// ws layout (bytes)
#define O_BLOB 0u
#define O_P2   15560000u         // partial2: 7*8192*4 = 229376 (gap before O_F)
#define O_F    16000000u
#define O_FS   43525120u
#define O_PART 43754496u

typedef __attribute__((ext_vector_type(8))) short bf16x8;
typedef __attribute__((ext_vector_type(4))) float f32x4;
typedef __attribute__((ext_vector_type(16))) float f32x16;
typedef __attribute__((ext_vector_type(2))) int i32x2;

union I4V { int4 i; bf16x8 v; unsigned u[4]; };
union C16 { f32x16 v; f32x4 q[4]; };

__device__ __forceinline__ unsigned short f2bf(float f) {
  unsigned u = __float_as_uint(f);
  u += 0x7fffu + ((u >> 16) & 1u);
  return (unsigned short)(u >> 16);
}
// input is already K2-scaled (weights/biases pre-multiplied by K2 at pack):
// tanh(x) = 1 - 2/(1+2^(K2 x)) -> no per-call multiply
__device__ __forceinline__ float fast_tanh_s(float xs) {
  float e = __builtin_amdgcn_exp2f(xs);
  return 1.0f - 2.0f * __builtin_amdgcn_rcpf(1.0f + e);
}
__device__ __forceinline__ unsigned pk_bf16(float a, float b) {
  unsigned r;
  asm("v_cvt_pk_bf16_f32 %0, %1, %2" : "=v"(r) : "v"(a), "v"(b));
  return r;
}
__device__ __forceinline__ void glds16(const void* g, void* l) {
  __builtin_amdgcn_global_load_lds(
      (const __attribute__((address_space(1))) unsigned int*)g,
      (__attribute__((address_space(3))) unsigned int*)l, 16, 0, 0);
}

// ---- inter-layer transition (verified R5 permlane mapping) ---------------
__device__ __forceinline__ void transition(const f32x16 (&acc)[4], bf16x8 (&bn)[8]) {
#pragma unroll
  for (int kk = 0; kk < 8; ++kk) {
    const int ms = kk >> 1, ko = (kk & 1) * 8;
    unsigned P0 = pk_bf16(fast_tanh_s(acc[ms][ko + 0]), fast_tanh_s(acc[ms][ko + 1]));
    unsigned P1 = pk_bf16(fast_tanh_s(acc[ms][ko + 2]), fast_tanh_s(acc[ms][ko + 3]));
    unsigned P2 = pk_bf16(fast_tanh_s(acc[ms][ko + 4]), fast_tanh_s(acc[ms][ko + 5]));
    unsigned P3 = pk_bf16(fast_tanh_s(acc[ms][ko + 6]), fast_tanh_s(acc[ms][ko + 7]));
    i32x2 s0 = __builtin_amdgcn_permlane32_swap((int)P0, (int)P2, false, false);
    i32x2 s1 = __builtin_amdgcn_permlane32_swap((int)P1, (int)P3, false, false);
    I4V r;
    r.u[0] = (unsigned)s0.x;   // w0
    r.u[1] = (unsigned)s1.x;   // w1
    r.u[2] = (unsigned)s0.y;   // w2
    r.u[3] = (unsigned)s1.y;   // w3
    bn[kk] = r.v;
  }
}

// ---- one hidden layer: K=128 as 8 k-slices; bias enters as C of kk=0 ------
__device__ __forceinline__ void hidden_layer(f32x16 (&acc)[4], const bf16x8 (&bn)[8],
                                             const uint8_t* wb, const float* biaL,
                                             int row, int hi, int hi4) {
  {
    int soff0 = (hi ^ (row & 15)) << 4;
#pragma unroll
    for (int mt = 0; mt < 4; ++mt) {
      bf16x8 aF = *(const bf16x8*)(wb + (mt * 32 + row) * 256 + soff0);
      C16 c0;
#pragma unroll
      for (int i = 0; i < 4; ++i)
        c0.q[i] = *(const f32x4*)(biaL + mt * 32 + i * 8 + hi4);
      acc[mt] = __builtin_amdgcn_mfma_f32_32x32x16_bf16(aF, bn[0], c0.v, 0, 0, 0);
    }
  }
#pragma unroll
  for (int kk = 1; kk < 8; ++kk) {
    int soff = ((2 * kk + hi) ^ (row & 15)) << 4;
#pragma unroll
    for (int mt = 0; mt < 4; ++mt) {
      bf16x8 aF = *(const bf16x8*)(wb + (mt * 32 + row) * 256 + soff);
      acc[mt] = __builtin_amdgcn_mfma_f32_32x32x16_bf16(aF, bn[kk], acc[mt], 0, 0, 0);
    }
  }
}

// ---------------- weight pack (R7 structure; K2 pre-scale only) ------------
__global__ __launch_bounds__(128) void k_pack(
    const float* __restrict__ W1, const float* __restrict__ Wh,
    const float* __restrict__ W1s, const float* __restrict__ Whs,
    const float* __restrict__ bh, const float* __restrict__ bhs,
    const float* __restrict__ Wo, const float* __restrict__ Wos,
    const float* __restrict__ bo, const float* __restrict__ bos,
    uint8_t* __restrict__ blob) {
  int bid = blockIdx.x;
  int e = bid / 3, sec = bid % 3;
  int n = threadIdx.x;
  uint8_t* be = blob + (size_t)e * BLOB_STRIDE;
  bool big = e < NE;
  int s = e - NE;
  if (sec == 0) {
    // W1k: 128 rows x 32B (K=16, real k 0..7, rest zero), scaled by K2
    union { int4 v[2]; unsigned short u[16]; } row;
    row.v[0] = make_int4(0, 0, 0, 0);
    row.v[1] = make_int4(0, 0, 0, 0);
    if (big) {
      for (int k = 0; k < NI; ++k) row.u[k] = f2bf(K2 * W1[((size_t)e * NI + k) * H + n]);
    } else {
      for (int k = 0; k < 2; ++k) row.u[k] = f2bf(K2 * W1s[((size_t)s * 2 + k) * H + n]);
    }
    *(int4*)(be + n * 32) = row.v[0];
    *(int4*)(be + n * 32 + 16) = row.v[1];
    // bias section: K2*bH0 | K2*bH1 | wo | bo   (wo/bo NOT scaled)
    float* bsec = (float*)(be + BIAS_OFF);
    bsec[n]       = K2 * (big ? bh[(size_t)e * H + n]        : bhs[(size_t)s * H + n]);
    bsec[128 + n] = K2 * (big ? bh[((size_t)NE + e) * H + n] : bhs[((size_t)NS + s) * H + n]);
    bsec[256 + n] = big ? Wo[(size_t)e * H + n] : Wos[(size_t)s * H + n];
    if (n == 0) bsec[384] = big ? bo[e] : bos[s];
  } else {
    int l = sec - 1;
    union { int4 v[16]; unsigned short u[128]; } row;
    if (big) {
      for (int k = 0; k < H; ++k)
        row.u[k] = f2bf(K2 * Wh[(((size_t)l * NE + e) * H + k) * H + n]);
    } else {
      for (int k = 0; k < H; ++k)
        row.u[k] = f2bf(K2 * Whs[(((size_t)l * NS + s) * H + k) * H + n]);
    }
    int4* dst = (int4*)(be + (l ? WH1_OFF : WH0_OFF) + n * 256);
    for (int c = 0; c < 16; ++c) dst[c] = row.v[c ^ (n & 15)];
  }
}

// ---------------- F build: normalize + gather, bf16 -----------------------
__global__ __launch_bounds__(256) void k_fbuild(
    const float* __restrict__ F_dist, const float* __restrict__ F_cos,
    const float* __restrict__ F_sin,
    const float* __restrict__ Zd, const float* __restrict__ Zc,
    const float* __restrict__ Zs,
    const int* __restrict__ IDX3, const int* __restrict__ IDX5,
    uint16_t* __restrict__ F, uint16_t* __restrict__ Fs) {
  int bid = blockIdx.x;
  int e = bid >> 5, tile = bid & 31;
  int b = tile * 256 + threadIdx.x;
  if (e < NE) {
    float cv = (F_cos[(size_t)b * NE + e] - Zc[e]) / Zc[NE + e];
    float sv = (F_sin[(size_t)b * NE + e] - Zs[e]) / Zs[NE + e];
    union { int4 v; unsigned short u[8]; } o;
    for (int j = 0; j < 6; ++j) {
      int id = IDX3[e * 6 + j];
      float x = (F_dist[(size_t)b * 45 + id] - Zd[id]) / Zd[45 + id];
      o.u[j] = f2bf(x);
    }
    o.u[6] = f2bf(cv);
    o.u[7] = f2bf(sv);
    *(int4*)(F + ((size_t)e * NB + b) * 8) = o.v;
  } else {
    int s = e - NE;
    int id = IDX5[s];
    float cv = (F_cos[(size_t)b * NE + id] - Zc[id]) / Zc[NE + id];
    float sv = (F_sin[(size_t)b * NE + id] - Zs[id]) / Zs[NE + id];
    unsigned o = (unsigned)f2bf(cv) | ((unsigned)f2bf(sv) << 16);
    *(unsigned*)(Fs + ((size_t)s * NB + b) * 2) = o;
  }
}

// ---------------- main: 3-layer MLP, 32x32x16 MFMA, h in registers --------
__global__ __launch_bounds__(512, 4) void k_main(
    const uint8_t* __restrict__ blob,
    const uint16_t* __restrict__ F, const uint16_t* __restrict__ Fs,
    const float* __restrict__ b1, const float* __restrict__ b1s,
    float* __restrict__ partial) {
  extern __shared__ __attribute__((aligned(16))) uint8_t smem[];
  // smem: [0:2K bias/wo][2048: Wh0 32K][34816: Wh1 32K]

  int bid = blockIdx.x;
  const int TOT = NEXP * NTILE;    // 6944, divisible by 8
  int lb = (bid & 7) * (TOT >> 3) + (bid >> 3);   // XCD-chunked swizzle
  int e = lb >> 5;
  int tile = lb & 31;
  int brow = tile * BT;

  int t = threadIdx.x;
  int w = t >> 6, lane = t & 63;
  int row = lane & 31, hi = lane >> 5;
  int hi4 = hi << 2;

  bool big = e < NE;
  int s = e - NE;
  const uint8_t* be = blob + (size_t)e * BLOB_STRIDE;

  // ---- early VMEM (issued BEFORE glds: in-order vmcnt => waiting on these
  //      does not drain the staging queue; L1+transition overlap staging) ----
  I4V bfr;
  bfr.i = make_int4(0, 0, 0, 0);
  if (hi == 0) {
    if (big) {
      bfr.i = *(const int4*)(F + ((size_t)e * NB + brow + w * 32 + row) * 8);
    } else {
      bfr.u[0] = *(const unsigned*)(Fs + ((size_t)s * NB + brow + w * 32 + row) * 2);
    }
  }
  const float* bias1 = big ? b1 + (size_t)e * H : b1s + (size_t)s * H;
  I4V aW[4];
  C16 c1[4];
#pragma unroll
  for (int mt = 0; mt < 4; ++mt) {
    aW[mt].i = *(const int4*)(be + (mt * 32 + row) * 32 + hi * 16);
#pragma unroll
    for (int i = 0; i < 4; ++i) {
      f32x4 q = *(const f32x4*)(bias1 + mt * 32 + i * 8 + hi4);
      c1[mt].q[i] = q * K2;     // acc1 = K2*(W1 F + b1)
    }
  }
  __builtin_amdgcn_sched_barrier(0);

  // ---- phase A staging: bias(2) + Wh0(32) chunks; phase B: Wh1(32) -------
  for (int c = w; c < 34; c += 8)
    glds16(be + BIAS_OFF + c * 1024 + lane * 16, smem + c * 1024);
  __builtin_amdgcn_sched_barrier(0);
  for (int c = 34 + w; c < 66; c += 8)
    glds16(be + BIAS_OFF + c * 1024 + lane * 16, smem + c * 1024);
  __builtin_amdgcn_sched_barrier(0);

  // ---- layer 1 (K=16, real 8; hi=1 half zero), no LDS: overlaps staging --
  f32x16 acc[4];
#pragma unroll
  for (int mt = 0; mt < 4; ++mt)
    acc[mt] = __builtin_amdgcn_mfma_f32_32x32x16_bf16(aW[mt].v, bfr.v, c1[mt].v, 0, 0, 0);

  bf16x8 bn[8];
  transition(acc, bn);

  // A done (the 4 youngest VMEM ops are always the Wh1 glds) -> layer 0 can
  // run while Wh1 is still in flight.
  asm volatile("s_waitcnt vmcnt(4)" ::: "memory");
  __builtin_amdgcn_s_barrier();
  __builtin_amdgcn_sched_barrier(0);

  hidden_layer(acc, bn, smem + 2048, (const float*)smem, row, hi, hi4);
  transition(acc, bn);

  asm volatile("s_waitcnt vmcnt(0)" ::: "memory");
  __builtin_amdgcn_s_barrier();
  __builtin_amdgcn_sched_barrier(0);

  hidden_layer(acc, bn, smem + 34816, (const float*)(smem + 512), row, hi, hi4);

  // ---- output layer: out = bo + sum wo[f]*tanh (acc already K2-scaled) ----
  {
    const float* woL = (const float*)(smem + 1024);
    float bout = *(const float*)(smem + 1536);
    float sum = 0.f;
#pragma unroll
    for (int mt = 0; mt < 4; ++mt)
#pragma unroll
      for (int i = 0; i < 4; ++i) {
        f32x4 wq = *(const f32x4*)(woL + mt * 32 + i * 8 + hi4);
#pragma unroll
        for (int j = 0; j < 4; ++j)
          sum += fast_tanh_s(acc[mt][4 * i + j]) * wq[j];
      }
    sum += __shfl_xor(sum, 32);
    if (hi == 0)
      partial[(size_t)e * NB + brow + w * 32 + row] = sum + bout;
  }
}

// ---------------- two-stage reduce over experts (217 = 7 x 31) ------------
__global__ __launch_bounds__(256) void k_reduce1(const float* __restrict__ partial,
                                                 float* __restrict__ partial2) {
  int g = blockIdx.x >> 5;         // 7 groups of 31 experts
  int b = (blockIdx.x & 31) * 256 + threadIdx.x;
  const float* p = partial + (size_t)g * 31 * NB + b;
  float s = 0.f;
#pragma unroll
  for (int e = 0; e < 31; ++e) s += p[(size_t)e * NB];
  partial2[(size_t)g * NB + b] = s;
}
__global__ __launch_bounds__(256) void k_reduce2(const float* __restrict__ partial2,
                                                 float* __restrict__ out) {
  int b = blockIdx.x * 256 + threadIdx.x;
  float s = 0.f;
#pragma unroll
  for (int g = 0; g < 7; ++g) s += partial2[(size_t)g * NB + b];
  out[b] = s;
}

extern "C" void kernel_launch(void* const* d_in, const int* in_sizes, int n_in,
                              void* d_out, int out_size, void* d_ws, size_t ws_size,
                              hipStream_t stream) {
  const float* F_dist = (const float*)d_in[0];
  const float* F_cos  = (const float*)d_in[1];
  const float* F_sin  = (const float*)d_in[2];
  // d_in[3] F_angle unused by reference
  const float* Zd  = (const float*)d_in[4];
  const float* Zc  = (const float*)d_in[5];
  const float* Zs  = (const float*)d_in[6];
  const int* IDX3  = (const int*)d_in[7];
  const int* IDX5  = (const int*)d_in[8];
  const float* W1  = (const float*)d_in[9];
  const float* b1  = (const float*)d_in[10];
  const float* Wh  = (const float*)d_in[11];
  const float* bh  = (const float*)d_in[12];
  const float* Wo  = (const float*)d_in[13];
  const float* bo  = (const float*)d_in[14];
  const float* W1s = (const float*)d_in[15];
  const float* b1s = (const float*)d_in[16];
  const float* Whs = (const float*)d_in[17];
  const float* bhs = (const float*)d_in[18];
  const float* Wos = (const float*)d_in[19];
  const float* bos = (const float*)d_in[20];

  uint8_t* ws = (uint8_t*)d_ws;
  uint8_t* blob = ws + O_BLOB;
  float* partial2 = (float*)(ws + O_P2);
  uint16_t* F   = (uint16_t*)(ws + O_F);
  uint16_t* Fs  = (uint16_t*)(ws + O_FS);
  float* partial = (float*)(ws + O_PART);

  hipFuncSetAttribute(reinterpret_cast<const void*>(k_main),
                      hipFuncAttributeMaxDynamicSharedMemorySize, SMEM_BYTES);

  k_pack<<<NEXP * 3, 128, 0, stream>>>(W1, Wh, W1s, Whs, bh, bhs, Wo, Wos, bo, bos, blob);
  k_fbuild<<<NEXP * 32, 256, 0, stream>>>(F_dist, F_cos, F_sin, Zd, Zc, Zs,
                                          IDX3, IDX5, F, Fs);
  k_main<<<NEXP * NTILE, 512, SMEM_BYTES, stream>>>(blob, F, Fs, b1, b1s, partial);
  k_reduce1<<<7 * 32, 256, 0, stream>>>(partial, partial2);
  k_reduce2<<<NB / 256, 256, 0, stream>>>(partial2, (float*)d_out);
}